// Round 2
// baseline (199.165 us; speedup 1.0000x reference)
//
#include <hip/hip_runtime.h>

#define GNN_IN 128
#define HID 256

// ---------------------------------------------------------------------------
// Detect whether edge_index is int64 (odd int32 words all zero since values
// < 10000) or int32. Writes 1 for int64, 0 for int32.
// ---------------------------------------------------------------------------
__global__ void detect_kernel(const unsigned int* __restrict__ ei,
                              unsigned int* __restrict__ flag) {
    if (threadIdx.x == 0 && blockIdx.x == 0) {
        unsigned int v = 0;
        for (int i = 1; i < 256; i += 2) v |= ei[i];
        *flag = (v == 0u) ? 1u : 0u;
    }
}

// ---------------------------------------------------------------------------
// Phase 1: A = x @ w1[0:128,:]  (blockIdx.y == 0)
//          B = x @ w1[128:256,:] (blockIdx.y == 1)
// Each block: 16 node-rows x 256 cols, 256 threads (thread = one column).
// ---------------------------------------------------------------------------
__global__ void __launch_bounds__(256) node_gemm_kernel(
    const float* __restrict__ x, const float* __restrict__ w1,
    float* __restrict__ AB, int num_nodes) {
    __shared__ float xs[16][GNN_IN];
    const int tid = threadIdx.x;
    const int r0  = blockIdx.x * 16;

    // stage 16x128 x-tile into LDS (float4 loads)
    for (int i = tid; i < 16 * GNN_IN / 4; i += 256) {
        const int rr = i >> 5;
        const int cc = (i & 31) << 2;
        int r = r0 + rr;
        if (r >= num_nodes) r = num_nodes - 1;  // safe clamp (10000%16==0 anyway)
        *(float4*)&xs[rr][cc] = *(const float4*)(x + (size_t)r * GNN_IN + cc);
    }
    __syncthreads();

    const float* w = w1 + (size_t)blockIdx.y * GNN_IN * HID;
    float acc[16];
#pragma unroll
    for (int r = 0; r < 16; ++r) acc[r] = 0.f;

#pragma unroll 4
    for (int k = 0; k < GNN_IN; ++k) {
        const float wv = w[(size_t)k * HID + tid];
#pragma unroll
        for (int r = 0; r < 16; ++r) acc[r] = fmaf(xs[r][k], wv, acc[r]);
    }

    float* ob = AB + (size_t)blockIdx.y * num_nodes * HID;
#pragma unroll
    for (int r = 0; r < 16; ++r) {
        if (r0 + r < num_nodes) ob[(size_t)(r0 + r) * HID + tid] = acc[r];
    }
}

// ---------------------------------------------------------------------------
// Phase 2: per-edge. One wave per edge; lane holds columns 4*lane..4*lane+3.
// h = relu(A[row] + B[col] + ed @ w1[256:260,:] + b1); out = sigmoid(h@w2+b2)
// ---------------------------------------------------------------------------
__global__ void __launch_bounds__(256) edge_kernel(
    const float* __restrict__ A, const float* __restrict__ B,
    const void* __restrict__ ei, const float* __restrict__ ed,
    const float* __restrict__ w1, const float* __restrict__ b1,
    const float* __restrict__ w2, const float* __restrict__ b2,
    const unsigned int* __restrict__ flag,
    float* __restrict__ out, int num_edges, int num_nodes) {
    const int lane   = threadIdx.x & 63;
    const int wave   = (blockIdx.x * blockDim.x + threadIdx.x) >> 6;
    const int nwaves = (gridDim.x * blockDim.x) >> 6;
    const int c0     = lane << 2;

    const float4 w2v = *(const float4*)(w2 + c0);
    const float4 b1v = *(const float4*)(b1 + c0);
    float wt[4][4];
#pragma unroll
    for (int k = 0; k < 4; ++k)
        *(float4*)wt[k] = *(const float4*)(w1 + (size_t)(2 * GNN_IN + k) * HID + c0);
    const float b2v  = b2[0];
    const int   is64 = flag ? (int)(*flag) : 0;

    const float* w2p = (const float*)&w2v;
    const float* b1p = (const float*)&b1v;

    const int chunk = (num_edges + nwaves - 1) / nwaves;
    const int e0 = wave * chunk;
    const int e1 = min(num_edges, e0 + chunk);

    for (int e = e0; e < e1; ++e) {
        int row, col;
        if (is64) {
            const int4 v = ((const int4*)ei)[e];  // int64 pair, low words
            row = v.x; col = v.z;
        } else {
            const int2 v = ((const int2*)ei)[e];
            row = v.x; col = v.y;
        }
        row = min(max(row, 0), num_nodes - 1);
        col = min(max(col, 0), num_nodes - 1);

        const float4 edv = *(const float4*)(ed + (size_t)e * 4);
        const float4 av  = *(const float4*)(A + (size_t)row * HID + c0);
        const float4 bv  = *(const float4*)(B + (size_t)col * HID + c0);
        const float* ap  = (const float*)&av;
        const float* bp  = (const float*)&bv;
        const float* edp = (const float*)&edv;

        float p = 0.f;
#pragma unroll
        for (int jj = 0; jj < 4; ++jj) {
            float h = ap[jj] + bp[jj] + b1p[jj];
#pragma unroll
            for (int k = 0; k < 4; ++k) h = fmaf(edp[k], wt[k][jj], h);
            h = fmaxf(h, 0.f);
            p = fmaf(h, w2p[jj], p);
        }
#pragma unroll
        for (int off = 32; off >= 1; off >>= 1) p += __shfl_xor(p, off, 64);
        if (lane == 0) out[e] = 1.f / (1.f + __expf(-(p + b2v)));
    }
}

// ---------------------------------------------------------------------------
// Fallback (ws too small): direct per-edge computation of the full 260x256.
// ---------------------------------------------------------------------------
__global__ void __launch_bounds__(256) edge_direct_kernel(
    const float* __restrict__ x, const void* __restrict__ ei,
    const float* __restrict__ ed, const float* __restrict__ w1,
    const float* __restrict__ b1, const float* __restrict__ w2,
    const float* __restrict__ b2, const unsigned int* __restrict__ flag,
    float* __restrict__ out, int num_edges, int num_nodes) {
    const int lane   = threadIdx.x & 63;
    const int wave   = (blockIdx.x * blockDim.x + threadIdx.x) >> 6;
    const int nwaves = (gridDim.x * blockDim.x) >> 6;
    const int c0     = lane << 2;

    const float4 w2v = *(const float4*)(w2 + c0);
    const float4 b1v = *(const float4*)(b1 + c0);
    float wt[4][4];
#pragma unroll
    for (int k = 0; k < 4; ++k)
        *(float4*)wt[k] = *(const float4*)(w1 + (size_t)(2 * GNN_IN + k) * HID + c0);
    const float b2v  = b2[0];
    const int   is64 = flag ? (int)(*flag) : 0;

    const float* w2p = (const float*)&w2v;
    const float* b1p = (const float*)&b1v;

    const int chunk = (num_edges + nwaves - 1) / nwaves;
    const int e0 = wave * chunk;
    const int e1 = min(num_edges, e0 + chunk);

    for (int e = e0; e < e1; ++e) {
        int row, col;
        if (is64) {
            const int4 v = ((const int4*)ei)[e];
            row = v.x; col = v.z;
        } else {
            const int2 v = ((const int2*)ei)[e];
            row = v.x; col = v.y;
        }
        row = min(max(row, 0), num_nodes - 1);
        col = min(max(col, 0), num_nodes - 1);

        const float4 edv = *(const float4*)(ed + (size_t)e * 4);
        const float* edp = (const float*)&edv;

        float h4[4];
#pragma unroll
        for (int jj = 0; jj < 4; ++jj) {
            float h = b1p[jj];
#pragma unroll
            for (int k = 0; k < 4; ++k) h = fmaf(edp[k], wt[k][jj], h);
            h4[jj] = h;
        }
        const float* xr = x + (size_t)row * GNN_IN;
        const float* xc = x + (size_t)col * GNN_IN;
        for (int k = 0; k < GNN_IN; ++k) {
            const float xv = xr[k];
            const float4 wv = *(const float4*)(w1 + (size_t)k * HID + c0);
            h4[0] = fmaf(xv, wv.x, h4[0]); h4[1] = fmaf(xv, wv.y, h4[1]);
            h4[2] = fmaf(xv, wv.z, h4[2]); h4[3] = fmaf(xv, wv.w, h4[3]);
        }
        for (int k = 0; k < GNN_IN; ++k) {
            const float xv = xc[k];
            const float4 wv = *(const float4*)(w1 + (size_t)(GNN_IN + k) * HID + c0);
            h4[0] = fmaf(xv, wv.x, h4[0]); h4[1] = fmaf(xv, wv.y, h4[1]);
            h4[2] = fmaf(xv, wv.z, h4[2]); h4[3] = fmaf(xv, wv.w, h4[3]);
        }
        float p = 0.f;
#pragma unroll
        for (int jj = 0; jj < 4; ++jj) {
            const float h = fmaxf(h4[jj], 0.f);
            p = fmaf(h, w2p[jj], p);
        }
#pragma unroll
        for (int off = 32; off >= 1; off >>= 1) p += __shfl_xor(p, off, 64);
        if (lane == 0) out[e] = 1.f / (1.f + __expf(-(p + b2v)));
    }
}

extern "C" void kernel_launch(void* const* d_in, const int* in_sizes, int n_in,
                              void* d_out, int out_size, void* d_ws, size_t ws_size,
                              hipStream_t stream) {
    const float* x  = (const float*)d_in[0];
    const void*  ei = d_in[1];
    const float* ed = (const float*)d_in[2];
    const float* w1 = (const float*)d_in[3];
    const float* b1 = (const float*)d_in[4];
    const float* w2 = (const float*)d_in[5];
    const float* b2 = (const float*)d_in[6];
    float* out = (float*)d_out;

    const int num_nodes = in_sizes[0] / GNN_IN;  // 10000
    const int num_edges = in_sizes[1] / 2;       // 640000

    unsigned int* flag = nullptr;
    if (ws_size >= 16) {
        flag = (unsigned int*)d_ws;
        detect_kernel<<<1, 64, 0, stream>>>((const unsigned int*)ei, flag);
    }

    const size_t need = 256 + (size_t)2 * num_nodes * HID * sizeof(float);
    if (ws_size >= need) {
        float* A = (float*)((char*)d_ws + 256);
        node_gemm_kernel<<<dim3((num_nodes + 15) / 16, 2), 256, 0, stream>>>(
            x, w1, A, num_nodes);
        float* Bp = A + (size_t)num_nodes * HID;
        edge_kernel<<<2048, 256, 0, stream>>>(A, Bp, ei, ed, w1, b1, w2, b2,
                                              flag, out, num_edges, num_nodes);
    } else {
        edge_direct_kernel<<<4096, 256, 0, stream>>>(x, ei, ed, w1, b1, w2, b2,
                                                     flag, out, num_edges, num_nodes);
    }
}

// Round 3
// 136.505 us; speedup vs baseline: 1.4590x; 1.4590x over previous
//
#include <hip/hip_runtime.h>
#include <hip/hip_fp16.h>

#define GNN_IN 128
#define HID 256

struct __align__(8) h4v { __half2 lo, hi; };

// ---------------------------------------------------------------------------
// Detect whether edge_index is int64 (odd int32 words all zero since values
// < 10000) or int32. Writes 1 for int64, 0 for int32.
// ---------------------------------------------------------------------------
__global__ void detect_kernel(const unsigned int* __restrict__ ei,
                              unsigned int* __restrict__ flag) {
    if (threadIdx.x == 0 && blockIdx.x == 0) {
        unsigned int v = 0;
        for (int i = 1; i < 256; i += 2) v |= ei[i];
        *flag = (v == 0u) ? 1u : 0u;
    }
}

// ---------------------------------------------------------------------------
// Phase 1: A = x @ w1[0:128,:]  (blockIdx.y == 0)
//          B = x @ w1[128:256,:] (blockIdx.y == 1)
// Output stored as fp16 to halve the edge-phase gather traffic.
// ---------------------------------------------------------------------------
__global__ void __launch_bounds__(256) node_gemm_kernel(
    const float* __restrict__ x, const float* __restrict__ w1,
    __half* __restrict__ AB, int num_nodes) {
    __shared__ float xs[16][GNN_IN];
    const int tid = threadIdx.x;
    const int r0  = blockIdx.x * 16;

    for (int i = tid; i < 16 * GNN_IN / 4; i += 256) {
        const int rr = i >> 5;
        const int cc = (i & 31) << 2;
        int r = r0 + rr;
        if (r >= num_nodes) r = num_nodes - 1;
        *(float4*)&xs[rr][cc] = *(const float4*)(x + (size_t)r * GNN_IN + cc);
    }
    __syncthreads();

    const float* w = w1 + (size_t)blockIdx.y * GNN_IN * HID;
    float acc[16];
#pragma unroll
    for (int r = 0; r < 16; ++r) acc[r] = 0.f;

#pragma unroll 4
    for (int k = 0; k < GNN_IN; ++k) {
        const float wv = w[(size_t)k * HID + tid];
#pragma unroll
        for (int r = 0; r < 16; ++r) acc[r] = fmaf(xs[r][k], wv, acc[r]);
    }

    __half* ob = AB + (size_t)blockIdx.y * num_nodes * HID;
#pragma unroll
    for (int r = 0; r < 16; ++r) {
        if (r0 + r < num_nodes) ob[(size_t)(r0 + r) * HID + tid] = __float2half_rn(acc[r]);
    }
}

// ---------------------------------------------------------------------------
// Phase 2: one wave per edge, lane holds 4 columns (8 B fp16 per gather).
// 2 edges per iteration: all loads issued up front to double MLP.
// ---------------------------------------------------------------------------
__global__ void __launch_bounds__(256) edge_kernel_fp16(
    const __half* __restrict__ A, const __half* __restrict__ B,
    const void* __restrict__ ei, const float* __restrict__ ed,
    const float* __restrict__ w1, const float* __restrict__ b1,
    const float* __restrict__ w2, const float* __restrict__ b2,
    const unsigned int* __restrict__ flag,
    float* __restrict__ out, int num_edges, int num_nodes) {
    const int lane   = threadIdx.x & 63;
    const int wave   = (blockIdx.x * blockDim.x + threadIdx.x) >> 6;
    const int nwaves = (gridDim.x * blockDim.x) >> 6;
    const int c0     = lane << 2;

    const float4 w2v = *(const float4*)(w2 + c0);
    const float4 b1v = *(const float4*)(b1 + c0);
    float wt[4][4];
#pragma unroll
    for (int k = 0; k < 4; ++k)
        *(float4*)wt[k] = *(const float4*)(w1 + (size_t)(2 * GNN_IN + k) * HID + c0);
    const float b2v  = b2[0];
    const int   is64 = (int)(*flag);

    const float* w2p = (const float*)&w2v;
    const float* b1p = (const float*)&b1v;

    const int chunk = (num_edges + nwaves - 1) / nwaves;
    const int e0 = wave * chunk;
    const int e1 = min(num_edges, e0 + chunk);

    for (int e = e0; e < e1; e += 2) {
        const int eb = (e + 1 < e1) ? (e + 1) : e;  // duplicate on tail
        int r0i, c0i, r1i, c1i;
        if (is64) {
            const int4 v0 = ((const int4*)ei)[e];
            const int4 v1 = ((const int4*)ei)[eb];
            r0i = v0.x; c0i = v0.z; r1i = v1.x; c1i = v1.z;
        } else {
            const int2 v0 = ((const int2*)ei)[e];
            const int2 v1 = ((const int2*)ei)[eb];
            r0i = v0.x; c0i = v0.y; r1i = v1.x; c1i = v1.y;
        }
        // issue all 4 gathers + 2 ed loads back-to-back (independent)
        const h4v  a0 = *(const h4v*)(A + (size_t)r0i * HID + c0);
        const h4v  bb0 = *(const h4v*)(B + (size_t)c0i * HID + c0);
        const h4v  a1 = *(const h4v*)(A + (size_t)r1i * HID + c0);
        const h4v  bb1 = *(const h4v*)(B + (size_t)c1i * HID + c0);
        const float4 ed0 = *(const float4*)(ed + (size_t)e * 4);
        const float4 ed1 = *(const float4*)(ed + (size_t)eb * 4);

        float p0 = 0.f, p1 = 0.f;
        {
            const float2 al = __half22float2(a0.lo), ah = __half22float2(a0.hi);
            const float2 bl = __half22float2(bb0.lo), bh = __half22float2(bb0.hi);
            const float af[4] = {al.x, al.y, ah.x, ah.y};
            const float bf[4] = {bl.x, bl.y, bh.x, bh.y};
#pragma unroll
            for (int jj = 0; jj < 4; ++jj) {
                float h = af[jj] + bf[jj] + b1p[jj];
                h = fmaf(ed0.x, wt[0][jj], h);
                h = fmaf(ed0.y, wt[1][jj], h);
                h = fmaf(ed0.z, wt[2][jj], h);
                h = fmaf(ed0.w, wt[3][jj], h);
                h = fmaxf(h, 0.f);
                p0 = fmaf(h, w2p[jj], p0);
            }
        }
        {
            const float2 al = __half22float2(a1.lo), ah = __half22float2(a1.hi);
            const float2 bl = __half22float2(bb1.lo), bh = __half22float2(bb1.hi);
            const float af[4] = {al.x, al.y, ah.x, ah.y};
            const float bf[4] = {bl.x, bl.y, bh.x, bh.y};
#pragma unroll
            for (int jj = 0; jj < 4; ++jj) {
                float h = af[jj] + bf[jj] + b1p[jj];
                h = fmaf(ed1.x, wt[0][jj], h);
                h = fmaf(ed1.y, wt[1][jj], h);
                h = fmaf(ed1.z, wt[2][jj], h);
                h = fmaf(ed1.w, wt[3][jj], h);
                h = fmaxf(h, 0.f);
                p1 = fmaf(h, w2p[jj], p1);
            }
        }
#pragma unroll
        for (int off = 32; off >= 1; off >>= 1) {
            p0 += __shfl_xor(p0, off, 64);
            p1 += __shfl_xor(p1, off, 64);
        }
        if (lane == 0) {
            out[e] = 1.f / (1.f + __expf(-(p0 + b2v)));
            if (eb != e) out[eb] = 1.f / (1.f + __expf(-(p1 + b2v)));
        }
    }
}

// ---------------------------------------------------------------------------
// Fallback (ws too small): direct per-edge computation of the full 260x256.
// ---------------------------------------------------------------------------
__global__ void __launch_bounds__(256) edge_direct_kernel(
    const float* __restrict__ x, const void* __restrict__ ei,
    const float* __restrict__ ed, const float* __restrict__ w1,
    const float* __restrict__ b1, const float* __restrict__ w2,
    const float* __restrict__ b2, const unsigned int* __restrict__ flag,
    float* __restrict__ out, int num_edges, int num_nodes) {
    const int lane   = threadIdx.x & 63;
    const int wave   = (blockIdx.x * blockDim.x + threadIdx.x) >> 6;
    const int nwaves = (gridDim.x * blockDim.x) >> 6;
    const int c0     = lane << 2;

    const float4 w2v = *(const float4*)(w2 + c0);
    const float4 b1v = *(const float4*)(b1 + c0);
    float wt[4][4];
#pragma unroll
    for (int k = 0; k < 4; ++k)
        *(float4*)wt[k] = *(const float4*)(w1 + (size_t)(2 * GNN_IN + k) * HID + c0);
    const float b2v  = b2[0];
    const int   is64 = flag ? (int)(*flag) : 0;

    const float* w2p = (const float*)&w2v;
    const float* b1p = (const float*)&b1v;

    const int chunk = (num_edges + nwaves - 1) / nwaves;
    const int e0 = wave * chunk;
    const int e1 = min(num_edges, e0 + chunk);

    for (int e = e0; e < e1; ++e) {
        int row, col;
        if (is64) {
            const int4 v = ((const int4*)ei)[e];
            row = v.x; col = v.z;
        } else {
            const int2 v = ((const int2*)ei)[e];
            row = v.x; col = v.y;
        }
        row = min(max(row, 0), num_nodes - 1);
        col = min(max(col, 0), num_nodes - 1);

        const float4 edv = *(const float4*)(ed + (size_t)e * 4);
        const float* edp = (const float*)&edv;

        float h4[4];
#pragma unroll
        for (int jj = 0; jj < 4; ++jj) {
            float h = b1p[jj];
#pragma unroll
            for (int k = 0; k < 4; ++k) h = fmaf(edp[k], wt[k][jj], h);
            h4[jj] = h;
        }
        const float* xr = x + (size_t)row * GNN_IN;
        const float* xc = x + (size_t)col * GNN_IN;
        for (int k = 0; k < GNN_IN; ++k) {
            const float xv = xr[k];
            const float4 wv = *(const float4*)(w1 + (size_t)k * HID + c0);
            h4[0] = fmaf(xv, wv.x, h4[0]); h4[1] = fmaf(xv, wv.y, h4[1]);
            h4[2] = fmaf(xv, wv.z, h4[2]); h4[3] = fmaf(xv, wv.w, h4[3]);
        }
        for (int k = 0; k < GNN_IN; ++k) {
            const float xv = xc[k];
            const float4 wv = *(const float4*)(w1 + (size_t)(GNN_IN + k) * HID + c0);
            h4[0] = fmaf(xv, wv.x, h4[0]); h4[1] = fmaf(xv, wv.y, h4[1]);
            h4[2] = fmaf(xv, wv.z, h4[2]); h4[3] = fmaf(xv, wv.w, h4[3]);
        }
        float p = 0.f;
#pragma unroll
        for (int jj = 0; jj < 4; ++jj) {
            const float h = fmaxf(h4[jj], 0.f);
            p = fmaf(h, w2p[jj], p);
        }
#pragma unroll
        for (int off = 32; off >= 1; off >>= 1) p += __shfl_xor(p, off, 64);
        if (lane == 0) out[e] = 1.f / (1.f + __expf(-(p + b2v)));
    }
}

extern "C" void kernel_launch(void* const* d_in, const int* in_sizes, int n_in,
                              void* d_out, int out_size, void* d_ws, size_t ws_size,
                              hipStream_t stream) {
    const float* x  = (const float*)d_in[0];
    const void*  ei = d_in[1];
    const float* ed = (const float*)d_in[2];
    const float* w1 = (const float*)d_in[3];
    const float* b1 = (const float*)d_in[4];
    const float* w2 = (const float*)d_in[5];
    const float* b2 = (const float*)d_in[6];
    float* out = (float*)d_out;

    const int num_nodes = in_sizes[0] / GNN_IN;  // 10000
    const int num_edges = in_sizes[1] / 2;       // 640000

    unsigned int* flag = nullptr;
    if (ws_size >= 16) {
        flag = (unsigned int*)d_ws;
        detect_kernel<<<1, 64, 0, stream>>>((const unsigned int*)ei, flag);
    }

    const size_t need = 256 + (size_t)2 * num_nodes * HID * sizeof(__half);
    if (flag && ws_size >= need) {
        __half* A = (__half*)((char*)d_ws + 256);
        node_gemm_kernel<<<dim3((num_nodes + 15) / 16, 2), 256, 0, stream>>>(
            x, w1, A, num_nodes);
        __half* Bp = A + (size_t)num_nodes * HID;
        edge_kernel_fp16<<<2048, 256, 0, stream>>>(A, Bp, ei, ed, w1, b1, w2, b2,
                                                   flag, out, num_edges, num_nodes);
    } else {
        edge_direct_kernel<<<4096, 256, 0, stream>>>(x, ei, ed, w1, b1, w2, b2,
                                                     flag, out, num_edges, num_nodes);
    }
}